// Round 6
// baseline (234.920 us; speedup 1.0000x reference)
//
#include <hip/hip_runtime.h>

// Multires hash-grid encode (2D, instant-NGP style). Round 6.
// Structure: repack_dense (new) -> level_pass4 -> transpose_out.
//
// Bottleneck model (R2/R3/R5 evidence): pass 1 is bound by a fixed per-CU
// divergent-gather request rate (~2.4 cy/lane-request; invariant to ILP,
// occupancy, and L2 locality). Only reducing REQUEST COUNT can help.
//  - Hashed levels (6..15): 4 random 8-B gathers/point/level — irreducible.
//  - Dense levels (0..5): corners (00,01) and (10,11) are ADJACENT entries.
//    Pass 0 repacks the 351,462 dense entries into float4 pairs
//    ptab[i] = (tbl[i], tbl[i+1]) in ws scratch (5.6 MB, 16-B aligned), so
//    each dense level costs 2 aligned 16-B gathers instead of 4 -> total
//    requests/point 64 -> 52 (-19%).
//    (i+1 never escapes the needed range: max consumed index is size-1,
//    max paired base is size-2; tbl[351462] exists so no OOB.)
// XCD partitioning kept (blockIdx%8 heuristic, perf-only). ws streams use
// nontemporal ops so they don't evict L2-resident tables.
// Index math bit-exact vs the jax reference (validated R1-R5).

static constexpr int kPoints = 524288;
static constexpr int kLevels = 16;
static constexpr unsigned kDenseTotal = 351462u;  // level_off[6]

__constant__ unsigned c_level_off[kLevels] = {
    0u, 289u, 1378u, 5603u, 22244u, 88293u, 351462u,
    875771u, 1400080u, 1924389u, 2448698u, 2973007u,
    3497316u, 4021625u, 4545934u, 5070243u
};

typedef unsigned int v4u __attribute__((ext_vector_type(4)));

__device__ __forceinline__ void nt_store_f2(float2* p, float2 v) {
    union { float2 f; unsigned long long u; } c; c.f = v;
    __builtin_nontemporal_store(c.u, (unsigned long long*)p);
}
__device__ __forceinline__ float2 nt_load_f2(const float2* p) {
    union { float2 f; unsigned long long u; } c;
    c.u = __builtin_nontemporal_load((const unsigned long long*)p);
    return c.f;
}
__device__ __forceinline__ void nt_store_f4(float4* p, float4 v) {
    union { float4 f; v4u u; } c; c.f = v;
    __builtin_nontemporal_store(c.u, (v4u*)p);
}

// ---- Pass 0: pack dense-level corner pairs ------------------------------
__global__ __launch_bounds__(256) void repack_dense(
    const float2* __restrict__ tbl,
    float4* __restrict__ ptab)
{
    const unsigned i = blockIdx.x * 256 + threadIdx.x;
    if (i >= kDenseTotal) return;
    const float2 a = tbl[i];
    const float2 b = tbl[i + 1];   // tbl[351462] exists (hashed region)
    ptab[i] = make_float4(a.x, a.y, b.x, b.y);
}

// ---- Pass 1: level-major, XCD-partitioned, 4 points/thread --------------
__global__ __launch_bounds__(256) void level_pass4(
    const float2* __restrict__ x,
    const float2* __restrict__ tbl,
    const float4* __restrict__ ptab,   // packed dense pairs (or nullptr)
    float2* __restrict__ ws)
{
    const int b    = blockIdx.x;
    const int xcd  = b & 7;
    const int slot = b >> 3;            // 0..1023 per XCD

    int level, pblk;                    // pblk: 1024-point block, 0..511
    if (slot < 512) {
        level = 6 + xcd;                // hashed levels 6..13: one per XCD
        pblk  = slot;
    } else if (slot < 576) {
        level = 14;  pblk = xcd * 64 + (slot - 512);
    } else if (slot < 640) {
        level = 15;  pblk = xcd * 64 + (slot - 576);
    } else {
        const int d = xcd * 384 + (slot - 640);   // 0..3071
        level = d >> 9;                 // dense levels 0..5
        pblk  = d & 511;
    }

    const int t  = threadIdx.x;
    const int n0 = (pblk << 10) | t;

    const int   scale_i = 16 << level;
    const float scale_f = (float)scale_i;
    const unsigned base = c_level_off[level];

    float wx0[4], wx1[4], wy0[4], wy1[4];

    if (level >= 6 || ptab == nullptr) {
        // ---- hashed (or unpacked fallback) path: 4x 8-B gathers/point ----
        unsigned idx[4][4];
#pragma unroll
        for (int k = 0; k < 4; ++k) {
            const float2 p = x[n0 + (k << 8)];
            const float fx = p.x * scale_f;
            const float fy = p.y * scale_f;
            const unsigned ix0 = (unsigned)(int)fx;
            const unsigned iy0 = (unsigned)(int)fy;
            const unsigned ix1 = ix0 + 1u;

            const float ox = fx - (float)(int)ix0;
            const float oy = fy - (float)(int)iy0;
            wx1[k] = fminf(fmaxf(ox, 0.0f), 1.0f);
            wx0[k] = fminf(fmaxf(1.0f - ox, 0.0f), 1.0f);
            wy1[k] = fminf(fmaxf(oy, 0.0f), 1.0f);
            wy0[k] = fminf(fmaxf(1.0f - oy, 0.0f), 1.0f);

            if (level < 6) {
                const unsigned stride = (unsigned)(scale_i + 1);
                const unsigned i00 = ix0 * stride + iy0;
                idx[k][0] = i00;          idx[k][1] = i00 + 1u;
                idx[k][2] = i00 + stride; idx[k][3] = i00 + stride + 1u;
            } else {
                const unsigned long long prod0 = (unsigned long long)iy0 * 19349663ull;
                const unsigned long long prod1 = prod0 + 19349663ull;
                const unsigned hi0 = (unsigned)(prod0 >> 32), lo0 = (unsigned)prod0;
                const unsigned hi1 = (unsigned)(prod1 >> 32), lo1 = (unsigned)prod1;
                idx[k][0] = (hi0 * 352277u + (lo0 ^ ix0) % 524309u) % 524309u;
                idx[k][1] = (hi1 * 352277u + (lo1 ^ ix0) % 524309u) % 524309u;
                idx[k][2] = (hi0 * 352277u + (lo0 ^ (ix0 + 1u)) % 524309u) % 524309u;
                idx[k][3] = (hi1 * 352277u + (lo1 ^ (ix0 + 1u)) % 524309u) % 524309u;
            }
        }

        float2 v[4][4];
#pragma unroll
        for (int k = 0; k < 4; ++k)
#pragma unroll
            for (int c = 0; c < 4; ++c)
                v[k][c] = tbl[base + idx[k][c]];

#pragma unroll
        for (int k = 0; k < 4; ++k) {
            const float w00 = wx0[k] * wy0[k], w01 = wx0[k] * wy1[k];
            const float w10 = wx1[k] * wy0[k], w11 = wx1[k] * wy1[k];
            float2 r;
            r.x = w00 * v[k][0].x + w01 * v[k][1].x + w10 * v[k][2].x + w11 * v[k][3].x;
            r.y = w00 * v[k][0].y + w01 * v[k][1].y + w10 * v[k][2].y + w11 * v[k][3].y;
            nt_store_f2(&ws[(size_t)level * kPoints + n0 + (k << 8)], r);
        }
    } else {
        // ---- dense packed path: 2x 16-B gathers/point --------------------
        unsigned i00a[4];
#pragma unroll
        for (int k = 0; k < 4; ++k) {
            const float2 p = x[n0 + (k << 8)];
            const float fx = p.x * scale_f;
            const float fy = p.y * scale_f;
            const unsigned ix0 = (unsigned)(int)fx;
            const unsigned iy0 = (unsigned)(int)fy;

            const float ox = fx - (float)(int)ix0;
            const float oy = fy - (float)(int)iy0;
            wx1[k] = fminf(fmaxf(ox, 0.0f), 1.0f);
            wx0[k] = fminf(fmaxf(1.0f - ox, 0.0f), 1.0f);
            wy1[k] = fminf(fmaxf(oy, 0.0f), 1.0f);
            wy0[k] = fminf(fmaxf(1.0f - oy, 0.0f), 1.0f);

            const unsigned stride = (unsigned)(scale_i + 1);
            i00a[k] = ix0 * stride + iy0;
        }

        const unsigned stride = (unsigned)(scale_i + 1);
        float4 va[4], vb[4];
#pragma unroll
        for (int k = 0; k < 4; ++k) {
            va[k] = ptab[base + i00a[k]];            // (v00, v01)
            vb[k] = ptab[base + i00a[k] + stride];   // (v10, v11)
        }

#pragma unroll
        for (int k = 0; k < 4; ++k) {
            const float w00 = wx0[k] * wy0[k], w01 = wx0[k] * wy1[k];
            const float w10 = wx1[k] * wy0[k], w11 = wx1[k] * wy1[k];
            float2 r;
            r.x = w00 * va[k].x + w01 * va[k].z + w10 * vb[k].x + w11 * vb[k].z;
            r.y = w00 * va[k].y + w01 * va[k].w + w10 * vb[k].y + w11 * vb[k].w;
            nt_store_f2(&ws[(size_t)level * kPoints + n0 + (k << 8)], r);
        }
    }
}

// ---- Pass 2: LDS-tiled transpose ws[16][N] -> out[N][8] float4 ----------
static constexpr int kTStride = 257;

__global__ __launch_bounds__(256) void transpose_out(
    const float2* __restrict__ ws,
    float4* __restrict__ out)
{
    __shared__ float2 lds[kLevels * kTStride];

    const int t  = threadIdx.x;
    const int n0 = blockIdx.x * 256;

#pragma unroll
    for (int l = 0; l < kLevels; ++l)
        lds[l * kTStride + t] = nt_load_f2(&ws[(size_t)l * kPoints + n0 + t]);

    __syncthreads();

    float4* o = out + (size_t)n0 * 8;
#pragma unroll
    for (int k = 0; k < 8; ++k) {
        const int f  = k * 256 + t;
        const int nl = f >> 3;
        const int i  = t & 7;
        const float2 a = lds[(2 * i)     * kTStride + nl];
        const float2 b = lds[(2 * i + 1) * kTStride + nl];
        nt_store_f4(&o[f], make_float4(a.x, a.y, b.x, b.y));
    }
}

// ---- Fallback: single-pass (if ws too small for two-pass) ---------------
__global__ __launch_bounds__(256) void hashgrid_fwd(
    const float2* __restrict__ x,
    const float2* __restrict__ tbl,
    float4* __restrict__ out)
{
    const int n = blockIdx.x * blockDim.x + threadIdx.x;
    if (n >= kPoints) return;
    const float2 p = x[n];
    float acc[2 * kLevels];
#pragma unroll
    for (int l = 0; l < kLevels; ++l) {
        const int   scale_i = 16 << l;
        const float scale_f = (float)scale_i;
        const float fx = p.x * scale_f;
        const float fy = p.y * scale_f;
        const unsigned ix0 = (unsigned)(int)fx;
        const unsigned iy0 = (unsigned)(int)fy;
        const unsigned ix1 = ix0 + 1u;
        const float ox = fx - (float)(int)ix0;
        const float oy = fy - (float)(int)iy0;
        const float wx1 = fminf(fmaxf(ox, 0.0f), 1.0f);
        const float wx0 = fminf(fmaxf(1.0f - ox, 0.0f), 1.0f);
        const float wy1 = fminf(fmaxf(oy, 0.0f), 1.0f);
        const float wy0 = fminf(fmaxf(1.0f - oy, 0.0f), 1.0f);
        unsigned i00, i01, i10, i11;
        if (l < 6) {
            const unsigned stride = (unsigned)(scale_i + 1);
            i00 = ix0 * stride + iy0; i01 = i00 + 1u;
            i10 = i00 + stride;       i11 = i10 + 1u;
        } else {
            const unsigned long long prod0 = (unsigned long long)iy0 * 19349663ull;
            const unsigned long long prod1 = prod0 + 19349663ull;
            const unsigned hi0 = (unsigned)(prod0 >> 32), lo0 = (unsigned)prod0;
            const unsigned hi1 = (unsigned)(prod1 >> 32), lo1 = (unsigned)prod1;
            i00 = (hi0 * 352277u + (lo0 ^ ix0) % 524309u) % 524309u;
            i01 = (hi1 * 352277u + (lo1 ^ ix0) % 524309u) % 524309u;
            i10 = (hi0 * 352277u + (lo0 ^ ix1) % 524309u) % 524309u;
            i11 = (hi1 * 352277u + (lo1 ^ ix1) % 524309u) % 524309u;
        }
        const unsigned base = c_level_off[l];
        const float2 v00 = tbl[base + i00];
        const float2 v01 = tbl[base + i01];
        const float2 v10 = tbl[base + i10];
        const float2 v11 = tbl[base + i11];
        const float w00 = wx0 * wy0, w01 = wx0 * wy1;
        const float w10 = wx1 * wy0, w11 = wx1 * wy1;
        acc[2 * l + 0] = w00 * v00.x + w01 * v01.x + w10 * v10.x + w11 * v11.x;
        acc[2 * l + 1] = w00 * v00.y + w01 * v01.y + w10 * v10.y + w11 * v11.y;
    }
    float4* o = out + (size_t)n * 8;
#pragma unroll
    for (int i = 0; i < 8; ++i)
        o[i] = make_float4(acc[4 * i + 0], acc[4 * i + 1],
                           acc[4 * i + 2], acc[4 * i + 3]);
}

extern "C" void kernel_launch(void* const* d_in, const int* in_sizes, int n_in,
                              void* d_out, int out_size, void* d_ws, size_t ws_size,
                              hipStream_t stream) {
    const float2* x   = (const float2*)d_in[0];
    const float2* tbl = (const float2*)d_in[1];

    const size_t ws_out_bytes  = (size_t)kLevels * kPoints * sizeof(float2); // 64 MiB
    const size_t ws_pack_bytes = (size_t)kDenseTotal * sizeof(float4);       // 5.6 MB

    if (ws_size >= ws_out_bytes + ws_pack_bytes) {
        float2* ws   = (float2*)d_ws;
        float4* ptab = (float4*)((char*)d_ws + ws_out_bytes);
        repack_dense<<<(kDenseTotal + 255) / 256, 256, 0, stream>>>(tbl, ptab);
        level_pass4<<<kLevels * (kPoints / 1024), 256, 0, stream>>>(x, tbl, ptab, ws);
        transpose_out<<<kPoints / 256, 256, 0, stream>>>(ws, (float4*)d_out);
    } else if (ws_size >= ws_out_bytes) {
        float2* ws = (float2*)d_ws;
        level_pass4<<<kLevels * (kPoints / 1024), 256, 0, stream>>>(x, tbl, nullptr, ws);
        transpose_out<<<kPoints / 256, 256, 0, stream>>>(ws, (float4*)d_out);
    } else {
        hashgrid_fwd<<<kPoints / 256, 256, 0, stream>>>(x, tbl, (float4*)d_out);
    }
}